// Round 16
// baseline (146.946 us; speedup 1.0000x reference)
//
#include <hip/hip_runtime.h>
#include <hip/hip_bf16.h>

// Problem constants
#define SEQ   2048
#define INF_  512          // IN dim
#define HQ    16           // query heads
#define KVH   4            // kv heads
#define DH    64           // head dim
#define NQ    (HQ*DH)      // 1024
#define NKV   (KVH*DH)     // 256
#define OUTD  512

typedef short v8s __attribute__((ext_vector_type(8)));   // 8 bf16 (4 VGPRs)
typedef float v4f __attribute__((ext_vector_type(4)));   // 4 fp32 acc

static __device__ __forceinline__ float bf2f(unsigned short u) {
    union { unsigned int i; float f; } c;
    c.i = ((unsigned int)u) << 16;
    return c.f;
}
static __device__ __forceinline__ unsigned short f2bf(float f) {  // RNE
    union { float f; unsigned int i; } c; c.f = f;
    unsigned int lsb = (c.i >> 16) & 1u;
    c.i += 0x7fffu + lsb;
    return (unsigned short)(c.i >> 16);
}
static __device__ __forceinline__ unsigned int f2bf2(float lo, float hi) { // packed cvt
    union { __hip_bfloat162 h; unsigned int u; } c;
    c.h = __float22bfloat162_rn(make_float2(lo, hi));
    return c.u;
}
// pack two v4f (8 fp32) into one bf16x8 fragment
static __device__ __forceinline__ v8s pack8(v4f a, v4f b) {
    union { v8s s; uint4 u; } c;
    c.u = make_uint4(f2bf2(a[0], a[1]), f2bf2(a[2], a[3]),
                     f2bf2(b[0], b[1]), f2bf2(b[2], b[3]));
    return c.s;
}

// async global->LDS DMA, 16B per lane; lds base must be lane-invariant
static __device__ __forceinline__ void gll16(const void* g, void* l) {
    __builtin_amdgcn_global_load_lds(
        (const __attribute__((address_space(1))) void*)g,
        (__attribute__((address_space(3))) void*)l, 16, 0, 0);
}

// Stage one 64x64 tile from an FP32 row-major source into bf16 LDS with the
// XOR group swizzle (LDS slot s of row r holds k-group s^(r&7)) — identical
// layout to the old gll16-DMA bf16 path, but converts fp32->bf16 in-register
// during staging. Wave w stages rows w*16..w*16+15.
static __device__ __forceinline__ void stage_tile_f32(
    const float* __restrict__ src, int stride, int kb,
    unsigned short* ldsbase, int w, int lane)
{
#pragma unroll
    for (int i = 0; i < 2; i++) {
        const int rl = w * 16 + i * 8 + (lane >> 3);
        const int kc = ((lane & 7) ^ (rl & 7)) * 8;
        const float* sp = src + (size_t)rl * stride + kb + kc;
        float4 a = *(const float4*)(sp);
        float4 b = *(const float4*)(sp + 4);
        *(uint4*)(ldsbase + (w * 16 + i * 8) * 64 + lane * 8) =
            make_uint4(f2bf2(a.x, a.y), f2bf2(a.z, a.w),
                       f2bf2(b.x, b.y), f2bf2(b.z, b.w));
    }
}

#define QSCALE 0.180336880f   // 0.125 * log2(e): scores in log2 domain -> exp2

// ===========================================================================
// GEMM 1 (MFMA): QKV projection, FP32 in -> bf16 swizzled tile buffers.
// 64x64 tile, BK=64, reg-staged fp32->bf16 conversion (no cast kernel),
// double-buffered, single barrier/iter. Grid 32x24.
// ===========================================================================
__global__ __launch_bounds__(256, 4) void gemm_qkv(
    const float* __restrict__ x,
    const float* __restrict__ Wq,
    const float* __restrict__ Wk,
    const float* __restrict__ Wv,
    unsigned short* __restrict__ Qg,
    unsigned short* __restrict__ Kg,
    unsigned short* __restrict__ Vg)
{
    __shared__ unsigned short Asb[2][4096];
    __shared__ unsigned short Bsb[2][4096];

    const int m0 = blockIdx.x * 64;
    const int n0 = blockIdx.y * 64;

    const float* Bp; int role;   // 0=Q 1=K 2=V
    if (n0 < NQ)            { Bp = Wq + (size_t)n0 * INF_;              role = 0; }
    else if (n0 < NQ + NKV) { Bp = Wk + (size_t)(n0 - NQ) * INF_;       role = 1; }
    else                    { Bp = Wv + (size_t)(n0 - NQ - NKV) * INF_; role = 2; }

    const int tid = threadIdx.x;
    const int w = tid >> 6, lane = tid & 63;
    const int n = lane & 15, quad = lane >> 4;
    const int m7 = n & 7;
    const int r0w = (w & 1) * 32, c0w = (w >> 1) * 32;
    const float* Ap = x + (size_t)m0 * INF_;

    v4f acc[2][2];
#pragma unroll
    for (int rt = 0; rt < 2; rt++)
#pragma unroll
        for (int ct = 0; ct < 2; ct++) acc[rt][ct] = (v4f){0.f,0.f,0.f,0.f};

    stage_tile_f32(Ap, INF_, 0, &Asb[0][0], w, lane);
    stage_tile_f32(Bp, INF_, 0, &Bsb[0][0], w, lane);

    for (int kb = 0; kb < INF_; kb += 64) {
        const int buf = (kb >> 6) & 1;
        __syncthreads();   // staging of buf complete; guards buf^1 reuse
        if (kb + 64 < INF_) {
            stage_tile_f32(Ap, INF_, kb + 64, &Asb[buf ^ 1][0], w, lane);
            stage_tile_f32(Bp, INF_, kb + 64, &Bsb[buf ^ 1][0], w, lane);
        }
#pragma unroll
        for (int kk = 0; kk < 2; kk++) {
            const int gs = ((kk * 4 + quad) ^ m7) * 8;
            v8s a0 = *(const v8s*)&Asb[buf][(r0w + n) * 64 + gs];
            v8s a1 = *(const v8s*)&Asb[buf][(r0w + 16 + n) * 64 + gs];
            v8s b0 = *(const v8s*)&Bsb[buf][(c0w + n) * 64 + gs];
            v8s b1 = *(const v8s*)&Bsb[buf][(c0w + 16 + n) * 64 + gs];
            acc[0][0] = __builtin_amdgcn_mfma_f32_16x16x32_bf16(a0, b0, acc[0][0], 0, 0, 0);
            acc[0][1] = __builtin_amdgcn_mfma_f32_16x16x32_bf16(a0, b1, acc[0][1], 0, 0, 0);
            acc[1][0] = __builtin_amdgcn_mfma_f32_16x16x32_bf16(a1, b0, acc[1][0], 0, 0, 0);
            acc[1][1] = __builtin_amdgcn_mfma_f32_16x16x32_bf16(a1, b1, acc[1][1], 0, 0, 0);
        }
    }

    const int t = m0 >> 6;
    if (role == 0) {
        unsigned short* base = Qg + ((size_t)(t * 16 + (n0 >> 6))) * 4096;
#pragma unroll
        for (int rt = 0; rt < 2; rt++)
#pragma unroll
            for (int ct = 0; ct < 2; ct++)
#pragma unroll
                for (int reg = 0; reg < 4; reg++) {
                    const int r = r0w + rt * 16 + quad * 4 + reg;
                    const int d = c0w + ct * 16 + n;
                    base[r * 64 + (((d >> 3) ^ (r & 7)) * 8) + (d & 7)] =
                        f2bf(acc[rt][ct][reg] * QSCALE);
                }
    } else if (role == 1) {
        const int g = (n0 - NQ) >> 6;
        unsigned short* base = Kg + ((size_t)(g * 32 + t)) * 4096;
#pragma unroll
        for (int rt = 0; rt < 2; rt++)
#pragma unroll
            for (int ct = 0; ct < 2; ct++)
#pragma unroll
                for (int reg = 0; reg < 4; reg++) {
                    const int r = r0w + rt * 16 + quad * 4 + reg;
                    const int d = c0w + ct * 16 + n;
                    base[r * 64 + (((d >> 3) ^ (r & 7)) * 8) + (d & 7)] =
                        f2bf(acc[rt][ct][reg]);
                }
    } else {
        const int g = (n0 - NQ - NKV) >> 6;
        unsigned short* base = Vg + ((size_t)(g * 32 + t)) * 4096;
#pragma unroll
        for (int rt = 0; rt < 2; rt++)
#pragma unroll
            for (int ct = 0; ct < 2; ct++) {
                const int jb_ = r0w + rt * 16 + quad * 4;  // 4 consecutive j
                const int d = c0w + ct * 16 + n;
                const int p = (jb_ & 32) + (((jb_ >> 2) & 3) * 8) + (((jb_ >> 4) & 1) * 4);
                *(uint2*)&base[d * 64 + (((p >> 3) ^ (d & 7)) * 8) + (p & 7)] =
                    make_uint2(f2bf2(acc[rt][ct][0], acc[rt][ct][1]),
                               f2bf2(acc[rt][ct][2], acc[rt][ct][3]));
            }
    }
}

// ===========================================================================
// MFMA flash attention, 2 heads/block + 2-tile barriers (r13 base, 48.8 us).
// Round-16: FULL STAGGER SYMMETRY. r12 overlapped exp2_B with PV_A (+4%);
// the mask+exp2_A block (16 trans) still ran serial after QK_B. Now QK_B's
// 8 MFMAs interleave with mask_A+exp2_A per-jt (2 MFMA -> 4 exp2), and
// mask_B folds into phase 4's existing PV_A||exp2_B interleave. Same
// mechanism, no new registers.
// Grid 512 = 8 head-pairs x 8p x 2sp x 4g, 2 blocks/CU, LB(256,2).
// ===========================================================================
__global__ __launch_bounds__(256, 2) void attn_mfma(
    const unsigned short* __restrict__ Qg,
    const unsigned short* __restrict__ Kg,
    const unsigned short* __restrict__ Vg,
    unsigned short* __restrict__ Oh)      // 4 planes of SEQ*NQ bf16
{
    __shared__ unsigned short Ksb[2][8192];   // [buf][pair: 2 x 64x64 tiles]
    __shared__ unsigned short Vsb[2][8192];

    const int bx = blockIdx.x;
    const int hg = bx & 7;                 // head pair: heads 2hg, 2hg+1
    const int p  = (bx >> 3) & 7;
    const int sp = (bx >> 6) & 1;          // which 64-row half of the q-block
    const int g  = bx >> 7;
    const int tid = threadIdx.x;
    const int w = tid >> 6, lane = tid & 63;
    const int n = lane & 15, quad = lane >> 4;
    const int m7 = n & 7;
    const int fo0 = (quad ^ m7) * 8;       // fragment sub-offsets (swizzled)
    const int fo1 = ((quad + 4) ^ m7) * 8;

    v8s ones;
#pragma unroll
    for (int i = 0; i < 8; i++) ones[i] = (short)0x3F80;  // bf16 1.0
    const v4f z = (v4f){0.f,0.f,0.f,0.f};

    unsigned short* Ohp = Oh + (size_t)g * ((size_t)SEQ * NQ);

    // stage tile tt of group g into pair-slot (tt&1) of buffer b_
#define STAGE_TILE(b_, tt_) do {                                             \
        const size_t off_ = ((size_t)(g * 32 + (tt_))) * 4096 + w * 1024 + lane * 8; \
        unsigned short* kd_ = &Ksb[(b_)][((tt_) & 1) * 4096 + w * 1024];     \
        unsigned short* vd_ = &Vsb[(b_)][((tt_) & 1) * 4096 + w * 1024];     \
        gll16(Kg + off_,       kd_);                                         \
        gll16(Kg + off_ + 512, kd_ + 512);                                   \
        gll16(Vg + off_,       vd_);                                         \
        gll16(Vg + off_ + 512, vd_ + 512);                                   \
    } while (0)

    for (int half = 0; half < 2; half++) {
        const int qi2 = half ? (15 - p) : p;
        const int ext = 2 * qi2 + sp + 1;           // causal tile extent (>=1)
        const int npair = (ext + 1) >> 1;
        const int rowbase = qi2 * 128 + sp * 64 + w * 16;  // wave's 16 rows

        if (half) __syncthreads();   // all waves done with half-0 buffers

        // prologue: stage pair 0 -> buf 0 (first loop barrier drains DMA)
        STAGE_TILE(0, 0);
        if (1 < ext) STAGE_TILE(0, 1);

        // Q fragments for both heads (rows rowbase..rowbase+15)
        v8s qa0, qa1, qb0, qb1;
        {
            const unsigned short* rpA =
                Qg + ((size_t)((2 * qi2 + sp) * 16 + hg * 2)) * 4096 + (w * 16 + n) * 64;
            const unsigned short* rpB = rpA + 4096;
            qa0 = *(const v8s*)(rpA + fo0);
            qa1 = *(const v8s*)(rpA + fo1);
            qb0 = *(const v8s*)(rpB + fo0);
            qb1 = *(const v8s*)(rpB + fo1);
        }

        v4f LA = (v4f){0.f,0.f,0.f,0.f};
        v4f LB = (v4f){0.f,0.f,0.f,0.f};
        v4f OA[4], OB[4];
#pragma unroll
        for (int dt = 0; dt < 4; dt++) { OA[dt] = z; OB[dt] = z; }

        for (int ip = 0; ip < npair; ip++) {
            const int buf = ip & 1;
            __syncthreads();          // drains DMA; guards buf^1 reuse
            {
                const int t2 = 2 * ip + 2;
                if (t2 < ext) {
                    STAGE_TILE(buf ^ 1, t2);
                    if (t2 + 1 < ext) STAGE_TILE(buf ^ 1, t2 + 1);
                }
            }
            for (int u = 0; u < 2 && 2 * ip + u < ext; u++) {
                const int tt = 2 * ip + u;
                const unsigned short* Kb = &Ksb[buf][u * 4096];
                const unsigned short* Vb = &Vsb[buf][u * 4096];
                const int t0 = tt * 64;
                const bool diag = (t0 + 63 > rowbase);  // wave-uniform
                const int qg = rowbase + n;

                // --- Phase 1: K fragments (kept live) + QK_A ---
                v8s kf[4][2];
                v4f sa[4], sb[4];
                __builtin_amdgcn_s_setprio(1);
#pragma unroll
                for (int jt = 0; jt < 4; jt++) {
                    const int kr = (jt * 16 + n) * 64;
                    kf[jt][0] = *(const v8s*)&Kb[kr + fo0];
                    kf[jt][1] = *(const v8s*)&Kb[kr + fo1];
                    v4f ta = __builtin_amdgcn_mfma_f32_16x16x32_bf16(kf[jt][0], qa0, z, 0, 0, 0);
                    sa[jt] = __builtin_amdgcn_mfma_f32_16x16x32_bf16(kf[jt][1], qa1, ta, 0, 0, 0);
                }

                // --- Phase 2: QK_B (MFMA) interleaved with mask_A+exp2_A
                // (trans): per jt, 2 MFMAs then 4 exp2 on sa[jt] (which is
                // ready; independent chains feed both pipes). ---
#pragma unroll
                for (int jt = 0; jt < 4; jt++) {
                    v4f tb = __builtin_amdgcn_mfma_f32_16x16x32_bf16(kf[jt][0], qb0, z, 0, 0, 0);
                    sb[jt] = __builtin_amdgcn_mfma_f32_16x16x32_bf16(kf[jt][1], qb1, tb, 0, 0, 0);
                    if (diag) {
                        const int jg = t0 + jt * 16 + quad * 4;
#pragma unroll
                        for (int reg = 0; reg < 4; reg++)
                            sa[jt][reg] = (jg + reg <= qg) ? sa[jt][reg] : -INFINITY;
                    }
                    sa[jt][0] = __builtin_amdgcn_exp2f(sa[jt][0]);  // 2^-inf = 0
                    sa[jt][1] = __builtin_amdgcn_exp2f(sa[jt][1]);
                    sa[jt][2] = __builtin_amdgcn_exp2f(sa[jt][2]);
                    sa[jt][3] = __builtin_amdgcn_exp2f(sa[jt][3]);
                }
                __builtin_amdgcn_s_setprio(0);

                // --- Phase 3: pack_A ---
                v8s pA0 = pack8(sa[0], sa[1]);
                v8s pA1 = pack8(sa[2], sa[3]);

                // --- Phase 4: L_A + PV_A (MFMA) interleaved with mask_B +
                // exp2_B (trans) ---
                v8s vf[4][2];
                __builtin_amdgcn_s_setprio(1);
                LA = __builtin_amdgcn_mfma_f32_16x16x32_bf16(ones, pA0, LA, 0, 0, 0);
                LA = __builtin_amdgcn_mfma_f32_16x16x32_bf16(ones, pA1, LA, 0, 0, 0);
#pragma unroll
                for (int dt = 0; dt < 4; dt++) {
                    const int vr = (dt * 16 + n) * 64;
                    vf[dt][0] = *(const v8s*)&Vb[vr + fo0];
                    vf[dt][1] = *(const v8s*)&Vb[vr + fo1];
                    OA[dt] = __builtin_amdgcn_mfma_f32_16x16x32_bf16(vf[dt][0], pA0, OA[dt], 0, 0, 0);
                    OA[dt] = __builtin_amdgcn_mfma_f32_16x16x32_bf16(vf[dt][1], pA1, OA[dt], 0, 0, 0);
                    if (diag) {
                        const int jg = t0 + dt * 16 + quad * 4;
#pragma unroll
                        for (int reg = 0; reg < 4; reg++)
                            sb[dt][reg] = (jg + reg <= qg) ? sb[dt][reg] : -INFINITY;
                    }
                    sb[dt][0] = __builtin_amdgcn_exp2f(sb[dt][0]);
                    sb[dt][1] = __builtin_amdgcn_exp2f(sb[dt][1]);
                    sb[dt][2] = __builtin_amdgcn_exp2f(sb[dt][2]);
                    sb[dt][3] = __builtin_amdgcn_exp2f(sb[dt][3]);
                }

                // --- Phase 5: pack_B + L_B + PV_B (V-frags still live) ---
                v8s pB0 = pack8(sb[0], sb[1]);
                v8s pB1 = pack8(sb[2], sb[3]);
                LB = __builtin_amdgcn_mfma_f32_16x16x32_bf16(ones, pB0, LB, 0, 0, 0);
                LB = __builtin_amdgcn_mfma_f32_16x16x32_bf16(ones, pB1, LB, 0, 0, 0);
#pragma unroll
                for (int dt = 0; dt < 4; dt++) {
                    OB[dt] = __builtin_amdgcn_mfma_f32_16x16x32_bf16(vf[dt][0], pB0, OB[dt], 0, 0, 0);
                    OB[dt] = __builtin_amdgcn_mfma_f32_16x16x32_bf16(vf[dt][1], pB1, OB[dt], 0, 0, 0);
                }
                __builtin_amdgcn_s_setprio(0);
            }
        }

        // normalize (l complete per lane) & store bf16, both heads
        {
            const float invA = 0.25f / LA[0];   // j=0 always unmasked -> L>0
            const float invB = 0.25f / LB[0];
            const int row = rowbase + n;
            unsigned short* dA = Ohp + (size_t)row * NQ + (hg * 2) * DH + quad * 4;
            unsigned short* dB = dA + DH;
#pragma unroll
            for (int dt = 0; dt < 4; dt++) {
                uint2 pkA = make_uint2(f2bf2(OA[dt][0] * invA, OA[dt][1] * invA),
                                       f2bf2(OA[dt][2] * invA, OA[dt][3] * invA));
                *(uint2*)(dA + dt * 16) = pkA;
                uint2 pkB = make_uint2(f2bf2(OB[dt][0] * invB, OB[dt][1] * invB),
                                       f2bf2(OB[dt][2] * invB, OB[dt][3] * invB));
                *(uint2*)(dB + dt * 16) = pkB;
            }
        }
    }
#undef STAGE_TILE
}

// ===========================================================================
// GEMM 2 (MFMA): out[s][o] = sum_j (sum_g Oh[g])[s][j] * Wo[o][j]. fp32 out.
// Fused: 4-plane sum in A-staging, B staged from FP32 Wo with in-register
// cvt. 32x64 tile, BK=64, depth-1 prefetch. Grid 64x8 = 512 blocks (2/CU).
// ===========================================================================
__global__ __launch_bounds__(256, 4) void gemm_out(
    const unsigned short* __restrict__ Oh,
    const float* __restrict__ Wo,
    float* __restrict__ C)
{
    __shared__ unsigned short Asb[32][72];
    __shared__ unsigned short Bsb[64][72];

    const int m0 = blockIdx.x * 32;
    const int n0 = blockIdx.y * 64;
    const int tid = threadIdx.x;
    const int w = tid >> 6, lane = tid & 63;
    const int n = lane & 15, quad = lane >> 4;
    const int rw = (w & 1) * 16, cw = (w >> 1) * 32;
    const int ar = tid >> 3, akc = (tid & 7) * 8;
    const int br = tid >> 2, bkc = (tid & 3) * 16;

    v4f acc[2];
    acc[0] = (v4f){0.f,0.f,0.f,0.f};
    acc[1] = (v4f){0.f,0.f,0.f,0.f};

    const size_t plane = (size_t)SEQ * NQ;
    const size_t abase = (size_t)(m0 + ar) * NQ + akc;
    const float* bp = Wo + (size_t)(n0 + br) * NQ + bkc;

    uint4 ua[4];
#pragma unroll
    for (int g = 0; g < 4; g++) ua[g] = *(const uint4*)(Oh + g * plane + abase);
    float4 ub0 = *(const float4*)(bp),      ub1 = *(const float4*)(bp + 4);
    float4 ub2 = *(const float4*)(bp + 8),  ub3 = *(const float4*)(bp + 12);

    for (int kb = 0; kb < NQ; kb += 64) {
        __syncthreads();
        {
            unsigned int ow[4];
#pragma unroll
            for (int q = 0; q < 4; q++) {
                const unsigned int u0 = ((const unsigned int*)&ua[0])[q];
                const unsigned int u1 = ((const unsigned int*)&ua[1])[q];
                const unsigned int u2 = ((const unsigned int*)&ua[2])[q];
                const unsigned int u3 = ((const unsigned int*)&ua[3])[q];
                float lo = bf2f((unsigned short)(u0 & 0xffffu)) + bf2f((unsigned short)(u1 & 0xffffu))
                         + bf2f((unsigned short)(u2 & 0xffffu)) + bf2f((unsigned short)(u3 & 0xffffu));
                float hi = bf2f((unsigned short)(u0 >> 16)) + bf2f((unsigned short)(u1 >> 16))
                         + bf2f((unsigned short)(u2 >> 16)) + bf2f((unsigned short)(u3 >> 16));
                ow[q] = f2bf2(lo, hi);
            }
            *(uint4*)&Asb[ar][akc] = make_uint4(ow[0], ow[1], ow[2], ow[3]);
        }
        *(uint4*)&Bsb[br][bkc] =
            make_uint4(f2bf2(ub0.x, ub0.y), f2bf2(ub0.z, ub0.w),
                       f2bf2(ub1.x, ub1.y), f2bf2(ub1.z, ub1.w));
        *(uint4*)&Bsb[br][bkc + 8] =
            make_uint4(f2bf2(ub2.x, ub2.y), f2bf2(ub2.z, ub2.w),
                       f2bf2(ub3.x, ub3.y), f2bf2(ub3.z, ub3.w));
        __syncthreads();
        if (kb + 64 < NQ) {
#pragma unroll
            for (int g = 0; g < 4; g++)
                ua[g] = *(const uint4*)(Oh + g * plane + abase + kb + 64);
            ub0 = *(const float4*)(bp + kb + 64);
            ub1 = *(const float4*)(bp + kb + 64 + 4);
            ub2 = *(const float4*)(bp + kb + 64 + 8);
            ub3 = *(const float4*)(bp + kb + 64 + 12);
        }
#pragma unroll
        for (int kk = 0; kk < 2; kk++) {
            v8s a  = *(const v8s*)&Asb[rw + n][kk * 32 + quad * 8];
            v8s b0 = *(const v8s*)&Bsb[cw + n][kk * 32 + quad * 8];
            v8s b1 = *(const v8s*)&Bsb[cw + 16 + n][kk * 32 + quad * 8];
            acc[0] = __builtin_amdgcn_mfma_f32_16x16x32_bf16(a, b0, acc[0], 0, 0, 0);
            acc[1] = __builtin_amdgcn_mfma_f32_16x16x32_bf16(a, b1, acc[1], 0, 0, 0);
        }
    }

#pragma unroll
    for (int ct = 0; ct < 2; ct++)
#pragma unroll
        for (int reg = 0; reg < 4; reg++) {
            const int row = m0 + rw + quad * 4 + reg;
            const int col = n0 + cw + ct * 16 + n;
            C[(size_t)row * OUTD + col] = acc[ct][reg];
        }
}

// ===========================================================================
extern "C" void kernel_launch(void* const* d_in, const int* in_sizes, int n_in,
                              void* d_out, int out_size, void* d_ws, size_t ws_size,
                              hipStream_t stream) {
    const float* x  = (const float*)d_in[0];
    const float* Wq = (const float*)d_in[1];
    const float* Wk = (const float*)d_in[2];
    const float* Wv = (const float*)d_in[3];
    const float* Wo = (const float*)d_in[4];
    float* out = (float*)d_out;

    char* base = (char*)d_ws;
    unsigned short* Oh  = (unsigned short*)(base);               // 16 MB: 4 planes
    unsigned short* Qg  = (unsigned short*)(base + 16777216);
    unsigned short* Kg  = (unsigned short*)(base + 20971520);
    unsigned short* Vg  = (unsigned short*)(base + 22020096);

    dim3 blk(256);
    gemm_qkv<<<dim3(SEQ / 64, (NQ + 2 * NKV) / 64), blk, 0, stream>>>(
        x, Wq, Wk, Wv, Qg, Kg, Vg);
    attn_mfma<<<dim3(512), blk, 0, stream>>>(Qg, Kg, Vg, Oh);
    gemm_out<<<dim3(SEQ / 32, OUTD / 64), blk, 0, stream>>>(Oh, Wo, out);
}

// Round 17
// 132.782 us; speedup vs baseline: 1.1067x; 1.1067x over previous
//
#include <hip/hip_runtime.h>
#include <hip/hip_bf16.h>

// Problem constants
#define SEQ   2048
#define INF_  512          // IN dim
#define HQ    16           // query heads
#define KVH   4            // kv heads
#define DH    64           // head dim
#define NQ    (HQ*DH)      // 1024
#define NKV   (KVH*DH)     // 256
#define OUTD  512

typedef short v8s __attribute__((ext_vector_type(8)));   // 8 bf16 (4 VGPRs)
typedef float v4f __attribute__((ext_vector_type(4)));   // 4 fp32 acc

static __device__ __forceinline__ float bf2f(unsigned short u) {
    union { unsigned int i; float f; } c;
    c.i = ((unsigned int)u) << 16;
    return c.f;
}
static __device__ __forceinline__ unsigned short f2bf(float f) {  // RNE
    union { float f; unsigned int i; } c; c.f = f;
    unsigned int lsb = (c.i >> 16) & 1u;
    c.i += 0x7fffu + lsb;
    return (unsigned short)(c.i >> 16);
}
static __device__ __forceinline__ unsigned int f2bf2(float lo, float hi) { // packed cvt
    union { __hip_bfloat162 h; unsigned int u; } c;
    c.h = __float22bfloat162_rn(make_float2(lo, hi));
    return c.u;
}
// pack two v4f (8 fp32) into one bf16x8 fragment
static __device__ __forceinline__ v8s pack8(v4f a, v4f b) {
    union { v8s s; uint4 u; } c;
    c.u = make_uint4(f2bf2(a[0], a[1]), f2bf2(a[2], a[3]),
                     f2bf2(b[0], b[1]), f2bf2(b[2], b[3]));
    return c.s;
}

// async global->LDS DMA, 16B per lane; lds base must be lane-invariant
static __device__ __forceinline__ void gll16(const void* g, void* l) {
    __builtin_amdgcn_global_load_lds(
        (const __attribute__((address_space(1))) void*)g,
        (__attribute__((address_space(3))) void*)l, 16, 0, 0);
}

// Stage one 64x64 tile from an FP32 row-major source into bf16 LDS with the
// XOR group swizzle (LDS slot s of row r holds k-group s^(r&7)) — identical
// layout to the old gll16-DMA bf16 path, but converts fp32->bf16 in-register
// during staging. Wave w stages rows w*16..w*16+15.
static __device__ __forceinline__ void stage_tile_f32(
    const float* __restrict__ src, int stride, int kb,
    unsigned short* ldsbase, int w, int lane)
{
#pragma unroll
    for (int i = 0; i < 2; i++) {
        const int rl = w * 16 + i * 8 + (lane >> 3);
        const int kc = ((lane & 7) ^ (rl & 7)) * 8;
        const float* sp = src + (size_t)rl * stride + kb + kc;
        float4 a = *(const float4*)(sp);
        float4 b = *(const float4*)(sp + 4);
        *(uint4*)(ldsbase + (w * 16 + i * 8) * 64 + lane * 8) =
            make_uint4(f2bf2(a.x, a.y), f2bf2(a.z, a.w),
                       f2bf2(b.x, b.y), f2bf2(b.z, b.w));
    }
}

#define QSCALE 0.180336880f   // 0.125 * log2(e): scores in log2 domain -> exp2

// ===========================================================================
// GEMM 1 (MFMA): QKV projection, FP32 in -> bf16 swizzled tile buffers.
// 64x64 tile, BK=64, reg-staged fp32->bf16 conversion (no cast kernel),
// double-buffered, single barrier/iter. Grid 32x24.
// ===========================================================================
__global__ __launch_bounds__(256, 4) void gemm_qkv(
    const float* __restrict__ x,
    const float* __restrict__ Wq,
    const float* __restrict__ Wk,
    const float* __restrict__ Wv,
    unsigned short* __restrict__ Qg,
    unsigned short* __restrict__ Kg,
    unsigned short* __restrict__ Vg)
{
    __shared__ unsigned short Asb[2][4096];
    __shared__ unsigned short Bsb[2][4096];

    const int m0 = blockIdx.x * 64;
    const int n0 = blockIdx.y * 64;

    const float* Bp; int role;   // 0=Q 1=K 2=V
    if (n0 < NQ)            { Bp = Wq + (size_t)n0 * INF_;              role = 0; }
    else if (n0 < NQ + NKV) { Bp = Wk + (size_t)(n0 - NQ) * INF_;       role = 1; }
    else                    { Bp = Wv + (size_t)(n0 - NQ - NKV) * INF_; role = 2; }

    const int tid = threadIdx.x;
    const int w = tid >> 6, lane = tid & 63;
    const int n = lane & 15, quad = lane >> 4;
    const int m7 = n & 7;
    const int r0w = (w & 1) * 32, c0w = (w >> 1) * 32;
    const float* Ap = x + (size_t)m0 * INF_;

    v4f acc[2][2];
#pragma unroll
    for (int rt = 0; rt < 2; rt++)
#pragma unroll
        for (int ct = 0; ct < 2; ct++) acc[rt][ct] = (v4f){0.f,0.f,0.f,0.f};

    stage_tile_f32(Ap, INF_, 0, &Asb[0][0], w, lane);
    stage_tile_f32(Bp, INF_, 0, &Bsb[0][0], w, lane);

    for (int kb = 0; kb < INF_; kb += 64) {
        const int buf = (kb >> 6) & 1;
        __syncthreads();   // staging of buf complete; guards buf^1 reuse
        if (kb + 64 < INF_) {
            stage_tile_f32(Ap, INF_, kb + 64, &Asb[buf ^ 1][0], w, lane);
            stage_tile_f32(Bp, INF_, kb + 64, &Bsb[buf ^ 1][0], w, lane);
        }
#pragma unroll
        for (int kk = 0; kk < 2; kk++) {
            const int gs = ((kk * 4 + quad) ^ m7) * 8;
            v8s a0 = *(const v8s*)&Asb[buf][(r0w + n) * 64 + gs];
            v8s a1 = *(const v8s*)&Asb[buf][(r0w + 16 + n) * 64 + gs];
            v8s b0 = *(const v8s*)&Bsb[buf][(c0w + n) * 64 + gs];
            v8s b1 = *(const v8s*)&Bsb[buf][(c0w + 16 + n) * 64 + gs];
            acc[0][0] = __builtin_amdgcn_mfma_f32_16x16x32_bf16(a0, b0, acc[0][0], 0, 0, 0);
            acc[0][1] = __builtin_amdgcn_mfma_f32_16x16x32_bf16(a0, b1, acc[0][1], 0, 0, 0);
            acc[1][0] = __builtin_amdgcn_mfma_f32_16x16x32_bf16(a1, b0, acc[1][0], 0, 0, 0);
            acc[1][1] = __builtin_amdgcn_mfma_f32_16x16x32_bf16(a1, b1, acc[1][1], 0, 0, 0);
        }
    }

    const int t = m0 >> 6;
    if (role == 0) {
        unsigned short* base = Qg + ((size_t)(t * 16 + (n0 >> 6))) * 4096;
#pragma unroll
        for (int rt = 0; rt < 2; rt++)
#pragma unroll
            for (int ct = 0; ct < 2; ct++)
#pragma unroll
                for (int reg = 0; reg < 4; reg++) {
                    const int r = r0w + rt * 16 + quad * 4 + reg;
                    const int d = c0w + ct * 16 + n;
                    base[r * 64 + (((d >> 3) ^ (r & 7)) * 8) + (d & 7)] =
                        f2bf(acc[rt][ct][reg] * QSCALE);
                }
    } else if (role == 1) {
        const int g = (n0 - NQ) >> 6;
        unsigned short* base = Kg + ((size_t)(g * 32 + t)) * 4096;
#pragma unroll
        for (int rt = 0; rt < 2; rt++)
#pragma unroll
            for (int ct = 0; ct < 2; ct++)
#pragma unroll
                for (int reg = 0; reg < 4; reg++) {
                    const int r = r0w + rt * 16 + quad * 4 + reg;
                    const int d = c0w + ct * 16 + n;
                    base[r * 64 + (((d >> 3) ^ (r & 7)) * 8) + (d & 7)] =
                        f2bf(acc[rt][ct][reg]);
                }
    } else {
        const int g = (n0 - NQ - NKV) >> 6;
        unsigned short* base = Vg + ((size_t)(g * 32 + t)) * 4096;
#pragma unroll
        for (int rt = 0; rt < 2; rt++)
#pragma unroll
            for (int ct = 0; ct < 2; ct++) {
                const int jb_ = r0w + rt * 16 + quad * 4;  // 4 consecutive j
                const int d = c0w + ct * 16 + n;
                const int p = (jb_ & 32) + (((jb_ >> 2) & 3) * 8) + (((jb_ >> 4) & 1) * 4);
                *(uint2*)&base[d * 64 + (((p >> 3) ^ (d & 7)) * 8) + (p & 7)] =
                    make_uint2(f2bf2(acc[rt][ct][0], acc[rt][ct][1]),
                               f2bf2(acc[rt][ct][2], acc[rt][ct][3]));
            }
    }
}

// ===========================================================================
// MFMA flash attention, 2 heads/block + intra-wave head stagger + 2-tile
// barriers (round-13 kernel verbatim — session best: attn 48.8 us, total
// 133.3 us). Round-17 reverts round-16's stagger-symmetry (regressed to
// 63.5: phase-2 interleave broke QK_B's dense MFMA issue window; unlike
// phase 4, the interleaved streams there were not latency-mature).
// Grid 512 = 8 head-pairs x 8p x 2sp x 4g, 2 blocks/CU, LB(256,2).
// ===========================================================================
__global__ __launch_bounds__(256, 2) void attn_mfma(
    const unsigned short* __restrict__ Qg,
    const unsigned short* __restrict__ Kg,
    const unsigned short* __restrict__ Vg,
    unsigned short* __restrict__ Oh)      // 4 planes of SEQ*NQ bf16
{
    __shared__ unsigned short Ksb[2][8192];   // [buf][pair: 2 x 64x64 tiles]
    __shared__ unsigned short Vsb[2][8192];

    const int bx = blockIdx.x;
    const int hg = bx & 7;                 // head pair: heads 2hg, 2hg+1
    const int p  = (bx >> 3) & 7;
    const int sp = (bx >> 6) & 1;          // which 64-row half of the q-block
    const int g  = bx >> 7;
    const int tid = threadIdx.x;
    const int w = tid >> 6, lane = tid & 63;
    const int n = lane & 15, quad = lane >> 4;
    const int m7 = n & 7;
    const int fo0 = (quad ^ m7) * 8;       // fragment sub-offsets (swizzled)
    const int fo1 = ((quad + 4) ^ m7) * 8;

    v8s ones;
#pragma unroll
    for (int i = 0; i < 8; i++) ones[i] = (short)0x3F80;  // bf16 1.0
    const v4f z = (v4f){0.f,0.f,0.f,0.f};

    unsigned short* Ohp = Oh + (size_t)g * ((size_t)SEQ * NQ);

    // stage tile tt of group g into pair-slot (tt&1) of buffer b_
#define STAGE_TILE(b_, tt_) do {                                             \
        const size_t off_ = ((size_t)(g * 32 + (tt_))) * 4096 + w * 1024 + lane * 8; \
        unsigned short* kd_ = &Ksb[(b_)][((tt_) & 1) * 4096 + w * 1024];     \
        unsigned short* vd_ = &Vsb[(b_)][((tt_) & 1) * 4096 + w * 1024];     \
        gll16(Kg + off_,       kd_);                                         \
        gll16(Kg + off_ + 512, kd_ + 512);                                   \
        gll16(Vg + off_,       vd_);                                         \
        gll16(Vg + off_ + 512, vd_ + 512);                                   \
    } while (0)

    for (int half = 0; half < 2; half++) {
        const int qi2 = half ? (15 - p) : p;
        const int ext = 2 * qi2 + sp + 1;           // causal tile extent (>=1)
        const int npair = (ext + 1) >> 1;
        const int rowbase = qi2 * 128 + sp * 64 + w * 16;  // wave's 16 rows

        if (half) __syncthreads();   // all waves done with half-0 buffers

        // prologue: stage pair 0 -> buf 0 (first loop barrier drains DMA)
        STAGE_TILE(0, 0);
        if (1 < ext) STAGE_TILE(0, 1);

        // Q fragments for both heads (rows rowbase..rowbase+15)
        v8s qa0, qa1, qb0, qb1;
        {
            const unsigned short* rpA =
                Qg + ((size_t)((2 * qi2 + sp) * 16 + hg * 2)) * 4096 + (w * 16 + n) * 64;
            const unsigned short* rpB = rpA + 4096;
            qa0 = *(const v8s*)(rpA + fo0);
            qa1 = *(const v8s*)(rpA + fo1);
            qb0 = *(const v8s*)(rpB + fo0);
            qb1 = *(const v8s*)(rpB + fo1);
        }

        v4f LA = (v4f){0.f,0.f,0.f,0.f};
        v4f LB = (v4f){0.f,0.f,0.f,0.f};
        v4f OA[4], OB[4];
#pragma unroll
        for (int dt = 0; dt < 4; dt++) { OA[dt] = z; OB[dt] = z; }

        for (int ip = 0; ip < npair; ip++) {
            const int buf = ip & 1;
            __syncthreads();          // drains DMA; guards buf^1 reuse
            {
                const int t2 = 2 * ip + 2;
                if (t2 < ext) {
                    STAGE_TILE(buf ^ 1, t2);
                    if (t2 + 1 < ext) STAGE_TILE(buf ^ 1, t2 + 1);
                }
            }
            for (int u = 0; u < 2 && 2 * ip + u < ext; u++) {
                const int tt = 2 * ip + u;
                const unsigned short* Kb = &Ksb[buf][u * 4096];
                const unsigned short* Vb = &Vsb[buf][u * 4096];

                // --- Phase 1: K fragments (kept live) + QK_A ---
                v8s kf[4][2];
                v4f sa[4], sb[4];
                __builtin_amdgcn_s_setprio(1);
#pragma unroll
                for (int jt = 0; jt < 4; jt++) {
                    const int kr = (jt * 16 + n) * 64;
                    kf[jt][0] = *(const v8s*)&Kb[kr + fo0];
                    kf[jt][1] = *(const v8s*)&Kb[kr + fo1];
                    v4f ta = __builtin_amdgcn_mfma_f32_16x16x32_bf16(kf[jt][0], qa0, z, 0, 0, 0);
                    sa[jt] = __builtin_amdgcn_mfma_f32_16x16x32_bf16(kf[jt][1], qa1, ta, 0, 0, 0);
                }
                // --- Phase 2: QK_B (MFMA pipe; sa results mature meanwhile) ---
#pragma unroll
                for (int jt = 0; jt < 4; jt++) {
                    v4f tb = __builtin_amdgcn_mfma_f32_16x16x32_bf16(kf[jt][0], qb0, z, 0, 0, 0);
                    sb[jt] = __builtin_amdgcn_mfma_f32_16x16x32_bf16(kf[jt][1], qb1, tb, 0, 0, 0);
                }
                __builtin_amdgcn_s_setprio(0);

                // mask (diagonal tile only; wave-uniform branch), both heads
                const int t0 = tt * 64;
                if (t0 + 63 > rowbase) {
                    const int qg = rowbase + n;
#pragma unroll
                    for (int jt = 0; jt < 4; jt++) {
                        const int jg = t0 + jt * 16 + quad * 4;
#pragma unroll
                        for (int reg = 0; reg < 4; reg++) {
                            const bool keep = (jg + reg <= qg);
                            sa[jt][reg] = keep ? sa[jt][reg] : -INFINITY;
                            sb[jt][reg] = keep ? sb[jt][reg] : -INFINITY;
                        }
                    }
                }

                // --- Phase 3: exp2_A + pack_A (trans; QK_B still draining) ---
#pragma unroll
                for (int jt = 0; jt < 4; jt++)
#pragma unroll
                    for (int reg = 0; reg < 4; reg++)
                        sa[jt][reg] = __builtin_amdgcn_exp2f(sa[jt][reg]); // 2^-inf = 0
                v8s pA0 = pack8(sa[0], sa[1]);
                v8s pA1 = pack8(sa[2], sa[3]);

                // --- Phase 4: L_A + PV_A (MFMA) interleaved with exp2_B ---
                v8s vf[4][2];
                __builtin_amdgcn_s_setprio(1);
                LA = __builtin_amdgcn_mfma_f32_16x16x32_bf16(ones, pA0, LA, 0, 0, 0);
                LA = __builtin_amdgcn_mfma_f32_16x16x32_bf16(ones, pA1, LA, 0, 0, 0);
#pragma unroll
                for (int dt = 0; dt < 4; dt++) {
                    const int vr = (dt * 16 + n) * 64;
                    vf[dt][0] = *(const v8s*)&Vb[vr + fo0];
                    vf[dt][1] = *(const v8s*)&Vb[vr + fo1];
                    OA[dt] = __builtin_amdgcn_mfma_f32_16x16x32_bf16(vf[dt][0], pA0, OA[dt], 0, 0, 0);
                    OA[dt] = __builtin_amdgcn_mfma_f32_16x16x32_bf16(vf[dt][1], pA1, OA[dt], 0, 0, 0);
                    // 4 exp2_B issued between PV_A MFMA pairs (separate pipes)
                    sb[dt][0] = __builtin_amdgcn_exp2f(sb[dt][0]);
                    sb[dt][1] = __builtin_amdgcn_exp2f(sb[dt][1]);
                    sb[dt][2] = __builtin_amdgcn_exp2f(sb[dt][2]);
                    sb[dt][3] = __builtin_amdgcn_exp2f(sb[dt][3]);
                }

                // --- Phase 5: pack_B + L_B + PV_B (V-frags still live) ---
                v8s pB0 = pack8(sb[0], sb[1]);
                v8s pB1 = pack8(sb[2], sb[3]);
                LB = __builtin_amdgcn_mfma_f32_16x16x32_bf16(ones, pB0, LB, 0, 0, 0);
                LB = __builtin_amdgcn_mfma_f32_16x16x32_bf16(ones, pB1, LB, 0, 0, 0);
#pragma unroll
                for (int dt = 0; dt < 4; dt++) {
                    OB[dt] = __builtin_amdgcn_mfma_f32_16x16x32_bf16(vf[dt][0], pB0, OB[dt], 0, 0, 0);
                    OB[dt] = __builtin_amdgcn_mfma_f32_16x16x32_bf16(vf[dt][1], pB1, OB[dt], 0, 0, 0);
                }
                __builtin_amdgcn_s_setprio(0);
            }
        }

        // normalize (l complete per lane) & store bf16, both heads
        {
            const float invA = 0.25f / LA[0];   // j=0 always unmasked -> L>0
            const float invB = 0.25f / LB[0];
            const int row = rowbase + n;
            unsigned short* dA = Ohp + (size_t)row * NQ + (hg * 2) * DH + quad * 4;
            unsigned short* dB = dA + DH;
#pragma unroll
            for (int dt = 0; dt < 4; dt++) {
                uint2 pkA = make_uint2(f2bf2(OA[dt][0] * invA, OA[dt][1] * invA),
                                       f2bf2(OA[dt][2] * invA, OA[dt][3] * invA));
                *(uint2*)(dA + dt * 16) = pkA;
                uint2 pkB = make_uint2(f2bf2(OB[dt][0] * invB, OB[dt][1] * invB),
                                       f2bf2(OB[dt][2] * invB, OB[dt][3] * invB));
                *(uint2*)(dB + dt * 16) = pkB;
            }
        }
    }
#undef STAGE_TILE
}

// ===========================================================================
// GEMM 2 (MFMA): out[s][o] = sum_j (sum_g Oh[g])[s][j] * Wo[o][j]. fp32 out.
// Fused: 4-plane sum in A-staging, B staged from FP32 Wo with in-register
// cvt. 32x64 tile, BK=64, depth-1 prefetch. Grid 64x8 = 512 blocks (2/CU).
// ===========================================================================
__global__ __launch_bounds__(256, 4) void gemm_out(
    const unsigned short* __restrict__ Oh,
    const float* __restrict__ Wo,
    float* __restrict__ C)
{
    __shared__ unsigned short Asb[32][72];
    __shared__ unsigned short Bsb[64][72];

    const int m0 = blockIdx.x * 32;
    const int n0 = blockIdx.y * 64;
    const int tid = threadIdx.x;
    const int w = tid >> 6, lane = tid & 63;
    const int n = lane & 15, quad = lane >> 4;
    const int rw = (w & 1) * 16, cw = (w >> 1) * 32;
    const int ar = tid >> 3, akc = (tid & 7) * 8;
    const int br = tid >> 2, bkc = (tid & 3) * 16;

    v4f acc[2];
    acc[0] = (v4f){0.f,0.f,0.f,0.f};
    acc[1] = (v4f){0.f,0.f,0.f,0.f};

    const size_t plane = (size_t)SEQ * NQ;
    const size_t abase = (size_t)(m0 + ar) * NQ + akc;
    const float* bp = Wo + (size_t)(n0 + br) * NQ + bkc;

    uint4 ua[4];
#pragma unroll
    for (int g = 0; g < 4; g++) ua[g] = *(const uint4*)(Oh + g * plane + abase);
    float4 ub0 = *(const float4*)(bp),      ub1 = *(const float4*)(bp + 4);
    float4 ub2 = *(const float4*)(bp + 8),  ub3 = *(const float4*)(bp + 12);

    for (int kb = 0; kb < NQ; kb += 64) {
        __syncthreads();
        {
            unsigned int ow[4];
#pragma unroll
            for (int q = 0; q < 4; q++) {
                const unsigned int u0 = ((const unsigned int*)&ua[0])[q];
                const unsigned int u1 = ((const unsigned int*)&ua[1])[q];
                const unsigned int u2 = ((const unsigned int*)&ua[2])[q];
                const unsigned int u3 = ((const unsigned int*)&ua[3])[q];
                float lo = bf2f((unsigned short)(u0 & 0xffffu)) + bf2f((unsigned short)(u1 & 0xffffu))
                         + bf2f((unsigned short)(u2 & 0xffffu)) + bf2f((unsigned short)(u3 & 0xffffu));
                float hi = bf2f((unsigned short)(u0 >> 16)) + bf2f((unsigned short)(u1 >> 16))
                         + bf2f((unsigned short)(u2 >> 16)) + bf2f((unsigned short)(u3 >> 16));
                ow[q] = f2bf2(lo, hi);
            }
            *(uint4*)&Asb[ar][akc] = make_uint4(ow[0], ow[1], ow[2], ow[3]);
        }
        *(uint4*)&Bsb[br][bkc] =
            make_uint4(f2bf2(ub0.x, ub0.y), f2bf2(ub0.z, ub0.w),
                       f2bf2(ub1.x, ub1.y), f2bf2(ub1.z, ub1.w));
        *(uint4*)&Bsb[br][bkc + 8] =
            make_uint4(f2bf2(ub2.x, ub2.y), f2bf2(ub2.z, ub2.w),
                       f2bf2(ub3.x, ub3.y), f2bf2(ub3.z, ub3.w));
        __syncthreads();
        if (kb + 64 < NQ) {
#pragma unroll
            for (int g = 0; g < 4; g++)
                ua[g] = *(const uint4*)(Oh + g * plane + abase + kb + 64);
            ub0 = *(const float4*)(bp + kb + 64);
            ub1 = *(const float4*)(bp + kb + 64 + 4);
            ub2 = *(const float4*)(bp + kb + 64 + 8);
            ub3 = *(const float4*)(bp + kb + 64 + 12);
        }
#pragma unroll
        for (int kk = 0; kk < 2; kk++) {
            v8s a  = *(const v8s*)&Asb[rw + n][kk * 32 + quad * 8];
            v8s b0 = *(const v8s*)&Bsb[cw + n][kk * 32 + quad * 8];
            v8s b1 = *(const v8s*)&Bsb[cw + 16 + n][kk * 32 + quad * 8];
            acc[0] = __builtin_amdgcn_mfma_f32_16x16x32_bf16(a, b0, acc[0], 0, 0, 0);
            acc[1] = __builtin_amdgcn_mfma_f32_16x16x32_bf16(a, b1, acc[1], 0, 0, 0);
        }
    }

#pragma unroll
    for (int ct = 0; ct < 2; ct++)
#pragma unroll
        for (int reg = 0; reg < 4; reg++) {
            const int row = m0 + rw + quad * 4 + reg;
            const int col = n0 + cw + ct * 16 + n;
            C[(size_t)row * OUTD + col] = acc[ct][reg];
        }
}

// ===========================================================================
extern "C" void kernel_launch(void* const* d_in, const int* in_sizes, int n_in,
                              void* d_out, int out_size, void* d_ws, size_t ws_size,
                              hipStream_t stream) {
    const float* x  = (const float*)d_in[0];
    const float* Wq = (const float*)d_in[1];
    const float* Wk = (const float*)d_in[2];
    const float* Wv = (const float*)d_in[3];
    const float* Wo = (const float*)d_in[4];
    float* out = (float*)d_out;

    char* base = (char*)d_ws;
    unsigned short* Oh  = (unsigned short*)(base);               // 16 MB: 4 planes
    unsigned short* Qg  = (unsigned short*)(base + 16777216);
    unsigned short* Kg  = (unsigned short*)(base + 20971520);
    unsigned short* Vg  = (unsigned short*)(base + 22020096);

    dim3 blk(256);
    gemm_qkv<<<dim3(SEQ / 64, (NQ + 2 * NKV) / 64), blk, 0, stream>>>(
        x, Wq, Wk, Wv, Qg, Kg, Vg);
    attn_mfma<<<dim3(512), blk, 0, stream>>>(Qg, Kg, Vg, Oh);
    gemm_out<<<dim3(SEQ / 32, OUTD / 64), blk, 0, stream>>>(Oh, Wo, out);
}